// Round 1
// baseline (415.986 us; speedup 1.0000x reference)
//
#include <hip/hip_runtime.h>

// KPN 5x5 per-pixel convolution.
// frames: (B=16, N=1, C=3, H=256, W=256) fp32
// core:   (B=16, N=1, 25, C=3, H=256, W=256) fp32
// out:    (B=16, C=3, H=256, W=256) fp32
// Memory-bound on core (314.6 MB read once). Strategy: float4 everywhere on
// the core/output path; frame rows loaded once per tap-row and reused across
// the 5 horizontal taps.

constexpr int KS = 5;
constexpr int KK = KS * KS;
constexpr int NB = 16;
constexpr int NC = 3;
constexpr int NH = 256;
constexpr int NW = 256;
constexpr int W4 = NW / 4;          // 64 float4 per row
constexpr int PLANE = NH * NW;      // 65536

__global__ __launch_bounds__(256) void kpn_conv_kernel(
    const float* __restrict__ frames,
    const float* __restrict__ core,
    const int* __restrict__ rate_p,
    float* __restrict__ out)
{
    const int rate = rate_p[0];

    int t = blockIdx.x * 256 + threadIdx.x;
    int w4  = t & (W4 - 1);          // 0..63
    int rem = t >> 6;
    int h   = rem & (NH - 1);        // 0..255
    rem >>= 8;
    int c   = rem % NC;
    int b   = rem / NC;
    if (b >= NB) return;

    const int w0 = w4 * 4;

    // core flat idx = (b*KK + idx)*NC*PLANE + c*PLANE + h*NW + w
    const int core_idx_stride = NC * PLANE;                       // 196608
    const int cbase = b * KK * core_idx_stride + c * PLANE + h * NW + w0;
    const float4* __restrict__ core4 = reinterpret_cast<const float4*>(core);

    // frame flat idx = (b*NC + c)*PLANE + hh*NW + ww
    const int fbase = (b * NC + c) * PLANE;

    float4 acc = make_float4(0.f, 0.f, 0.f, 0.f);

    if (rate == 1) {
        // pad = 2
        #pragma unroll
        for (int i = 0; i < KS; ++i) {
            const int hh = h + i - 2;
            const bool hv = (hh >= 0) && (hh < NH);
            const float* __restrict__ frow = frames + fbase + hh * NW;
            // frame columns needed: w0-2 .. w0+5  (8 floats)
            float fr[8];
            #pragma unroll
            for (int k = 0; k < 8; ++k) {
                const int ww = w0 - 2 + k;
                fr[k] = (hv && ww >= 0 && ww < NW) ? frow[ww] : 0.f;
            }
            #pragma unroll
            for (int j = 0; j < KS; ++j) {
                const float4 cv = core4[(cbase + (i * KS + j) * core_idx_stride) >> 2];
                acc.x += cv.x * fr[j + 0];
                acc.y += cv.y * fr[j + 1];
                acc.z += cv.z * fr[j + 2];
                acc.w += cv.w * fr[j + 3];
            }
        }
    } else {
        // generic rate path (never hit by the harness, kept for correctness)
        const int pad = (KS / 2) * rate;
        for (int i = 0; i < KS; ++i) {
            const int hh = h + i * rate - pad;
            const bool hv = (hh >= 0) && (hh < NH);
            for (int j = 0; j < KS; ++j) {
                const float4 cv = core4[(cbase + (i * KS + j) * core_idx_stride) >> 2];
                float* ap = reinterpret_cast<float*>(&acc);
                const float* cp = reinterpret_cast<const float*>(&cv);
                #pragma unroll
                for (int k = 0; k < 4; ++k) {
                    const int ww = w0 + k + j * rate - pad;
                    const float fv = (hv && ww >= 0 && ww < NW)
                                         ? frames[fbase + hh * NW + ww] : 0.f;
                    ap[k] += cp[k] * fv;
                }
            }
        }
    }

    reinterpret_cast<float4*>(out)[(fbase + h * NW + w0) >> 2] = acc;
}

extern "C" void kernel_launch(void* const* d_in, const int* in_sizes, int n_in,
                              void* d_out, int out_size, void* d_ws, size_t ws_size,
                              hipStream_t stream) {
    const float* frames = (const float*)d_in[0];
    const float* core   = (const float*)d_in[1];
    const int*   rate   = (const int*)d_in[2];
    float* out = (float*)d_out;

    const int total_threads = NB * NC * NH * W4;   // 786432
    dim3 grid(total_threads / 256), block(256);
    hipLaunchKernelGGL(kpn_conv_kernel, grid, block, 0, stream,
                       frames, core, rate, out);
}

// Round 3
// 402.016 us; speedup vs baseline: 1.0348x; 1.0348x over previous
//
#include <hip/hip_runtime.h>

// KPN 5x5 per-pixel convolution.
// frames: (B=16, N=1, C=3, H=256, W=256) fp32   (12.6 MB, reused 5x -> cache)
// core:   (B=16, N=1, 25, C=3, H=256, W=256) fp32 (314.6 MB, streamed once -> nt)
// out:    (B=16, C=3, H=256, W=256) fp32
// One thread = 4 consecutive output pixels (float4). A 64-lane wave covers one
// full (b,c,h) row, so h-bounds branches are wave-uniform.

typedef float vf4 __attribute__((ext_vector_type(4)));  // native vec for nt builtins

constexpr int KS = 5;
constexpr int KK = KS * KS;
constexpr int NB = 16;
constexpr int NC = 3;
constexpr int NH = 256;
constexpr int NW = 256;
constexpr int W4 = NW / 4;          // 64 float4 per row
constexpr int PLANE = NH * NW;      // 65536

__global__ __launch_bounds__(256) void kpn_conv_kernel(
    const float* __restrict__ frames,
    const float* __restrict__ core,
    const int* __restrict__ rate_p,
    float* __restrict__ out)
{
    const int rate = rate_p[0];

    int t = blockIdx.x * 256 + threadIdx.x;
    const int w4 = t & (W4 - 1);     // 0..63  (== lane id)
    int rem = t >> 6;
    const int h  = rem & (NH - 1);   // wave-uniform
    rem >>= 8;
    const int c  = rem % NC;
    const int b  = rem / NC;
    if (b >= NB) return;

    const int w0 = w4 * 4;
    const int cis = NC * PLANE;      // stride between taps: 196608 floats
    const float* __restrict__ cptr  = core + (size_t)b * KK * cis
                                           + (size_t)c * PLANE + h * NW + w0;
    const float* __restrict__ fpl   = frames + (size_t)(b * NC + c) * PLANE;

    vf4 acc = (vf4)(0.f);

    if (rate == 1) {
        const bool okA = (w4 >= 1);          // left chunk in-bounds
        const bool okC = (w4 <= W4 - 2);     // right chunk in-bounds
        const int aoff = okA ? (w0 - 4) : 0;         // clamped, value masked below
        const int coff = okC ? (w0 + 4) : (NW - 4);

        #pragma unroll
        for (int i = 0; i < KS; ++i) {
            const int hh = h + i - 2;
            if (hh < 0 || hh >= NH) continue;        // wave-uniform skip: row is zero

            const float* __restrict__ frow = fpl + hh * NW;
            const vf4 Av = *reinterpret_cast<const vf4*>(frow + aoff);
            const vf4 Bv = *reinterpret_cast<const vf4*>(frow + w0);
            const vf4 Cv = *reinterpret_cast<const vf4*>(frow + coff);

            // window floats w0-2 .. w0+5
            float fr[8];
            fr[0] = okA ? Av.z : 0.f;
            fr[1] = okA ? Av.w : 0.f;
            fr[2] = Bv.x;  fr[3] = Bv.y;  fr[4] = Bv.z;  fr[5] = Bv.w;
            fr[6] = okC ? Cv.x : 0.f;
            fr[7] = okC ? Cv.y : 0.f;

            #pragma unroll
            for (int j = 0; j < KS; ++j) {
                const vf4 cv = __builtin_nontemporal_load(
                    reinterpret_cast<const vf4*>(cptr + (size_t)(i * KS + j) * cis));
                acc.x += cv.x * fr[j + 0];
                acc.y += cv.y * fr[j + 1];
                acc.z += cv.z * fr[j + 2];
                acc.w += cv.w * fr[j + 3];
            }
        }
    } else {
        // generic rate path (harness always passes rate=1; kept for correctness)
        const int pad = (KS / 2) * rate;
        for (int i = 0; i < KS; ++i) {
            const int hh = h + i * rate - pad;
            const bool hv = (hh >= 0) && (hh < NH);
            for (int j = 0; j < KS; ++j) {
                const vf4 cv = __builtin_nontemporal_load(
                    reinterpret_cast<const vf4*>(cptr + (size_t)(i * KS + j) * cis));
                #pragma unroll
                for (int k = 0; k < 4; ++k) {
                    const int ww = w0 + k + j * rate - pad;
                    const float fv = (hv && ww >= 0 && ww < NW)
                                         ? fpl[hh * NW + ww] : 0.f;
                    acc[k] += cv[k] * fv;
                }
            }
        }
    }

    vf4* __restrict__ optr = reinterpret_cast<vf4*>(
        out + (size_t)(b * NC + c) * PLANE + h * NW + w0);
    __builtin_nontemporal_store(acc, optr);
}

extern "C" void kernel_launch(void* const* d_in, const int* in_sizes, int n_in,
                              void* d_out, int out_size, void* d_ws, size_t ws_size,
                              hipStream_t stream) {
    const float* frames = (const float*)d_in[0];
    const float* core   = (const float*)d_in[1];
    const int*   rate   = (const int*)d_in[2];
    float* out = (float*)d_out;

    const int total_threads = NB * NC * NH * W4;   // 786432
    dim3 grid(total_threads / 256), block(256);
    hipLaunchKernelGGL(kpn_conv_kernel, grid, block, 0, stream,
                       frames, core, rate, out);
}

// Round 4
// 401.104 us; speedup vs baseline: 1.0371x; 1.0023x over previous
//
#include <hip/hip_runtime.h>

// KPN 5x5 per-pixel convolution.
// frames: (16,1,3,256,256) fp32   (12.6 MB, reused 5x -> cache)
// core:   (16,1,25,3,256,256) fp32 (314.6 MB, streamed once -> nontemporal)
// out:    (16,3,256,256) fp32
// One thread = 4 consecutive output pixels. MLP-max variant: all 25 core
// float4 loads hoisted before the FMA phase (core taps are never OOB; only
// frame values are zero-masked at borders), so each wave keeps 25 outstanding
// 1KB HBM requests in flight.

typedef float vf4 __attribute__((ext_vector_type(4)));

constexpr int KS = 5;
constexpr int KK = KS * KS;
constexpr int NB = 16;
constexpr int NC = 3;
constexpr int NH = 256;
constexpr int NW = 256;
constexpr int W4 = NW / 4;          // 64 float4 per row
constexpr int PLANE = NH * NW;      // 65536

__global__ __launch_bounds__(256, 1) void kpn_conv_kernel(
    const float* __restrict__ frames,
    const float* __restrict__ core,
    const int* __restrict__ rate_p,
    float* __restrict__ out)
{
    const int rate = rate_p[0];

    int t = blockIdx.x * 256 + threadIdx.x;
    const int w4 = t & (W4 - 1);     // 0..63  (== lane id)
    int rem = t >> 6;
    const int h  = rem & (NH - 1);   // wave-uniform
    rem >>= 8;
    const int c  = rem % NC;
    const int b  = rem / NC;
    if (b >= NB) return;

    const int w0 = w4 * 4;
    const int cis = NC * PLANE;      // stride between taps: 196608 floats
    const float* __restrict__ cptr  = core + (size_t)b * KK * cis
                                           + (size_t)c * PLANE + h * NW + w0;
    const float* __restrict__ fpl   = frames + (size_t)(b * NC + c) * PLANE;

    vf4 acc = (vf4)(0.f);

    if (rate == 1) {
        // ---- phase 1: issue all 25 core loads (never OOB) ----
        vf4 cv[KK];
        #pragma unroll
        for (int k = 0; k < KK; ++k)
            cv[k] = __builtin_nontemporal_load(
                reinterpret_cast<const vf4*>(cptr + (size_t)k * cis));

        // ---- phase 2: frame windows + FMA ----
        const bool okA = (w4 >= 1);          // left chunk in-bounds
        const bool okC = (w4 <= W4 - 2);     // right chunk in-bounds
        const int aoff = okA ? (w0 - 4) : 0;
        const int coff = okC ? (w0 + 4) : (NW - 4);

        #pragma unroll
        for (int i = 0; i < KS; ++i) {
            const int hh = h + i - 2;
            const bool hv = (hh >= 0) && (hh < NH);
            const float* __restrict__ frow = fpl + (hv ? hh : h) * NW;
            const vf4 Av = *reinterpret_cast<const vf4*>(frow + aoff);
            const vf4 Bv = *reinterpret_cast<const vf4*>(frow + w0);
            const vf4 Cv = *reinterpret_cast<const vf4*>(frow + coff);

            // window floats w0-2 .. w0+5, zero-masked at h/w borders
            float fr[8];
            fr[0] = (hv && okA) ? Av.z : 0.f;
            fr[1] = (hv && okA) ? Av.w : 0.f;
            fr[2] = hv ? Bv.x : 0.f;
            fr[3] = hv ? Bv.y : 0.f;
            fr[4] = hv ? Bv.z : 0.f;
            fr[5] = hv ? Bv.w : 0.f;
            fr[6] = (hv && okC) ? Cv.x : 0.f;
            fr[7] = (hv && okC) ? Cv.y : 0.f;

            #pragma unroll
            for (int j = 0; j < KS; ++j) {
                const vf4 cvv = cv[i * KS + j];
                acc.x += cvv.x * fr[j + 0];
                acc.y += cvv.y * fr[j + 1];
                acc.z += cvv.z * fr[j + 2];
                acc.w += cvv.w * fr[j + 3];
            }
        }
    } else {
        // generic rate path (harness always passes rate=1; kept for correctness)
        const int pad = (KS / 2) * rate;
        for (int i = 0; i < KS; ++i) {
            const int hh = h + i * rate - pad;
            const bool hv = (hh >= 0) && (hh < NH);
            for (int j = 0; j < KS; ++j) {
                const vf4 cvv = __builtin_nontemporal_load(
                    reinterpret_cast<const vf4*>(cptr + (size_t)(i * KS + j) * cis));
                #pragma unroll
                for (int k = 0; k < 4; ++k) {
                    const int ww = w0 + k + j * rate - pad;
                    const float fv = (hv && ww >= 0 && ww < NW)
                                         ? fpl[hh * NW + ww] : 0.f;
                    acc[k] += cvv[k] * fv;
                }
            }
        }
    }

    vf4* __restrict__ optr = reinterpret_cast<vf4*>(
        out + (size_t)(b * NC + c) * PLANE + h * NW + w0);
    __builtin_nontemporal_store(acc, optr);
}

extern "C" void kernel_launch(void* const* d_in, const int* in_sizes, int n_in,
                              void* d_out, int out_size, void* d_ws, size_t ws_size,
                              hipStream_t stream) {
    const float* frames = (const float*)d_in[0];
    const float* core   = (const float*)d_in[1];
    const int*   rate   = (const int*)d_in[2];
    float* out = (float*)d_out;

    const int total_threads = NB * NC * NH * W4;   // 786432
    dim3 grid(total_threads / 256), block(256);
    hipLaunchKernelGGL(kpn_conv_kernel, grid, block, 0, stream,
                       frames, core, rate, out);
}